// Round 8
// baseline (218.200 us; speedup 1.0000x reference)
//
#include <hip/hip_runtime.h>

#define N_NODES 50000
#define N_EDGES 800000
#define IN_CH   128
#define HID     128
#define OUT_CH  64

#define NBUCK 196
#define XPAD  136      // 128 bf16 + 8 pad: conflict-free MFMA frag reads

typedef __attribute__((ext_vector_type(8))) short bf16x8;
typedef __attribute__((ext_vector_type(4))) float f32x4;
typedef unsigned short ushort_t;

__device__ __forceinline__ unsigned short f2bf(float f) {
    unsigned u = __float_as_uint(f);
    u += 0x7fffu + ((u >> 16) & 1u);      // RNE
    return (unsigned short)(u >> 16);
}
__device__ __forceinline__ unsigned pack2(float a, float b) {
    return (unsigned)f2bf(a) | ((unsigned)f2bf(b) << 16);
}
__device__ __forceinline__ float bf_lo(unsigned u) { return __uint_as_float(u << 16); }
__device__ __forceinline__ float bf_hi(unsigned u) { return __uint_as_float(u & 0xffff0000u); }

// ========= setup: zero bucket counters/cursors + bf16-transpose weights =========

__global__ __launch_bounds__(256) void k_zero_prep(const float* __restrict__ W1,
                                                   const float* __restrict__ W2,
                                                   ushort_t* __restrict__ W1t,
                                                   ushort_t* __restrict__ W2t,
                                                   int* __restrict__ bcnt,
                                                   int* __restrict__ bcur) {
    if (blockIdx.x == 0) {
        for (int i = threadIdx.x; i < NBUCK; i += 256) { bcnt[i] = 0; bcur[i] = 0; }
    }
    int i = blockIdx.x * 256 + threadIdx.x;
    if (i < 128 * 128) {
        int k = i >> 7, c = i & 127;
        W1t[c * 128 + k] = f2bf(W1[k * 128 + c]);
    } else {
        int j = i - 128 * 128;
        if (j < 128 * 64) {
            int k = j >> 6, c = j & 63;
            W2t[c * 128 + k] = f2bf(W2[k * 64 + c]);
        }
    }
}

// ================= CSR build: two-level bucket sort =================

__global__ __launch_bounds__(256) void kb_hist(const int* __restrict__ dst,
                                               int* __restrict__ bcnt) {
    __shared__ int lh[NBUCK];
    for (int i = threadIdx.x; i < NBUCK; i += 256) lh[i] = 0;
    __syncthreads();
    int base = blockIdx.x * 8192;
#pragma unroll 4
    for (int k = 0; k < 32; ++k) {
        int e = base + k * 256 + threadIdx.x;
        if (e < N_EDGES) atomicAdd(&lh[dst[e] >> 8], 1);
    }
    __syncthreads();
    for (int i = threadIdx.x; i < NBUCK; i += 256)
        if (lh[i]) atomicAdd(&bcnt[i], lh[i]);
}

// scatter packed (ldst<<16)|src records into bucket runs; 196-scan computed locally
__global__ __launch_bounds__(256) void kb_scatter(const int* __restrict__ src,
                                                  const int* __restrict__ dst,
                                                  const int* __restrict__ bcnt,
                                                  int* __restrict__ bcur,
                                                  unsigned* __restrict__ rec) {
    __shared__ int s[256];
    __shared__ int sbase[NBUCK];
    __shared__ int lh[NBUCK];
    __shared__ int gbase[NBUCK];
    const int t = threadIdx.x;
    // local exclusive scan of the 196 bucket counts
    int v = (t < NBUCK) ? bcnt[t] : 0;
    s[t] = v;
    __syncthreads();
    for (int off = 1; off < 256; off <<= 1) {
        int u = (t >= off) ? s[t - off] : 0;
        __syncthreads();
        s[t] += u;
        __syncthreads();
    }
    if (t < NBUCK) sbase[t] = s[t] - v;
    for (int i = t; i < NBUCK; i += 256) lh[i] = 0;
    __syncthreads();

    int base = blockIdx.x * 4096;
#pragma unroll 4
    for (int k = 0; k < 16; ++k) {
        int e = base + k * 256 + t;
        if (e < N_EDGES) atomicAdd(&lh[dst[e] >> 8], 1);
    }
    __syncthreads();
    for (int i = t; i < NBUCK; i += 256) {
        int c = lh[i];
        gbase[i] = c ? (sbase[i] + atomicAdd(&bcur[i], c)) : 0;
    }
    __syncthreads();
    for (int i = t; i < NBUCK; i += 256) lh[i] = 0;
    __syncthreads();
#pragma unroll 4
    for (int k = 0; k < 16; ++k) {
        int e = base + k * 256 + t;
        if (e < N_EDGES) {
            int d = dst[e], b = d >> 8;
            int rk = atomicAdd(&lh[b], 1);
            rec[gbase[b] + rk] = (unsigned)src[e] | ((unsigned)(d & 255) << 16);
        }
    }
}

// per-bucket CSR: hist256 -> row_ptr/dis, fill private col slice. 196-scan local.
__global__ __launch_bounds__(256) void kc_csr(const int* __restrict__ bcnt,
                                              const unsigned* __restrict__ rec,
                                              int* __restrict__ row_ptr,
                                              float* __restrict__ dis,
                                              int* __restrict__ col) {
    __shared__ int s[256];
    __shared__ int lh[256];
    __shared__ int cur[256];
    const int b = blockIdx.x, t = threadIdx.x;
    // local exclusive scan for this bucket's base
    int v = (t < NBUCK) ? bcnt[t] : 0;
    s[t] = v;
    __syncthreads();
    for (int off = 1; off < 256; off <<= 1) {
        int u = (t >= off) ? s[t - off] : 0;
        __syncthreads();
        s[t] += u;
        __syncthreads();
    }
    __shared__ int lo_s, hi_s;
    if (t == b) { lo_s = s[t] - v; hi_s = s[t]; }
    __syncthreads();
    const int lo = lo_s, hi = hi_s;

    lh[t] = 0;
    __syncthreads();
    for (int j = lo + t; j < hi; j += 256)
        atomicAdd(&lh[rec[j] >> 16], 1);
    __syncthreads();
    int deg = lh[t];
    s[t] = deg;
    __syncthreads();
    for (int off = 1; off < 256; off <<= 1) {
        int u = (t >= off) ? s[t - off] : 0;
        __syncthreads();
        s[t] += u;
        __syncthreads();
    }
    int gp = lo + s[t] - deg;
    int node = (b << 8) + t;
    if (node < N_NODES) {
        row_ptr[node] = gp;
        dis[node] = rsqrtf((float)deg + 1.0f);
    }
    if (b == NBUCK - 1 && t == 0) row_ptr[N_NODES] = N_EDGES;
    cur[t] = gp;
    __syncthreads();
    for (int j = lo + t; j < hi; j += 256) {
        unsigned r = rec[j];
        int pos = atomicAdd(&cur[r >> 16], 1);
        col[pos] = (int)(r & 0xffffu);
    }
}

// ====== MFMA GEMM1: g1 = bf16((x @ W1) * dis[row]); 64 rows x 128 cols/block ======

__global__ __launch_bounds__(256) void k_gemm1(const float* __restrict__ x,
                                               const ushort_t* __restrict__ W1t,
                                               const float* __restrict__ dis,
                                               ushort_t* __restrict__ g) {
    __shared__ ushort_t xs[64 * XPAD];
    __shared__ ushort_t ws[128 * XPAD];
    const int tid = threadIdx.x;
    const int row0 = blockIdx.x * 64;

    for (int i = tid; i < 64 * 32; i += 256) {
        int r = i >> 5, k4 = (i & 31) << 2;
        int gr = row0 + r;
        float4 v = make_float4(0.f, 0.f, 0.f, 0.f);
        if (gr < N_NODES) v = *(const float4*)&x[(long)gr * IN_CH + k4];
        ushort4 u;
        u.x = f2bf(v.x); u.y = f2bf(v.y); u.z = f2bf(v.z); u.w = f2bf(v.w);
        *(ushort4*)&xs[r * XPAD + k4] = u;
    }
    for (int i = tid; i < 128 * 16; i += 256) {
        int c = i >> 4, seg = i & 15;
        *(uint4*)&ws[c * XPAD + seg * 8] = *(const uint4*)&W1t[c * 128 + seg * 8];
    }
    __syncthreads();

    const int w = tid >> 6, lane = tid & 63;
    const int m = lane & 15, q = lane >> 4;
    const ushort_t* arow = &xs[(w * 16 + m) * XPAD + q * 8];
    const ushort_t* brow = &ws[m * XPAD + q * 8];

    f32x4 acc[8] = {};
#pragma unroll
    for (int k0 = 0; k0 < 128; k0 += 32) {
        bf16x8 a = *(const bf16x8*)(arow + k0);
#pragma unroll
        for (int nt = 0; nt < 8; ++nt) {
            bf16x8 b = *(const bf16x8*)(brow + nt * 16 * XPAD + k0);
            acc[nt] = __builtin_amdgcn_mfma_f32_16x16x32_bf16(a, b, acc[nt], 0, 0, 0);
        }
    }

#pragma unroll
    for (int reg = 0; reg < 4; ++reg) {
        int gr = row0 + w * 16 + q * 4 + reg;
        if (gr < N_NODES) {
            float d = dis[gr];
#pragma unroll
            for (int nt = 0; nt < 8; ++nt)
                g[(long)gr * HID + nt * 16 + m] = f2bf(acc[nt][reg] * d);
        }
    }
}

// ====== fused layer-1 aggregate + GEMM2 ======
// block owns 64 dst rows: wave w gathers rows w*16..w*16+15 (bf16 gather, fp32 acc,
// relu+bias -> bf16 in LDS), then MFMA (a1_tile @ W2t) -> g3 with dis scaling.

__global__ __launch_bounds__(256) void k_aggmm(const int* __restrict__ row_ptr,
                                               const int* __restrict__ col,
                                               const float* __restrict__ dis,
                                               const ushort_t* __restrict__ g1,
                                               const float* __restrict__ b1,
                                               const ushort_t* __restrict__ W2t,
                                               ushort_t* __restrict__ g3) {
    __shared__ ushort_t a1s[64 * XPAD];   // relu'd layer-1 rows, bf16
    __shared__ ushort_t ws[64 * XPAD];    // W2t (64 cols x 128 k)
    const int tid = threadIdx.x;
    const int row0 = blockIdx.x * 64;
    const int w = tid >> 6, lane = tid & 63;
    const int q = lane >> 4;        // edge slot 0..3
    const int seg = lane & 15;      // 16B segment of the 256B row
    const int cl = seg << 3;
    const uint4* G = (const uint4*)g1;

    for (int i = tid; i < 64 * 16; i += 256) {
        int c = i >> 4, sg = i & 15;
        *(uint4*)&ws[c * XPAD + sg * 8] = *(const uint4*)&W2t[c * 128 + sg * 8];
    }

    // bias for this lane's 8 channels (only q==0 lanes use it)
    float4 bA = *(const float4*)&b1[cl];
    float4 bB = *(const float4*)&b1[cl + 4];

    for (int i = 0; i < 16; ++i) {
        int r = row0 + w * 16 + i;
        float acc[8] = {};
        if (r < N_NODES) {
            const int beg = row_ptr[r], end = row_ptr[r + 1];
            int e = beg + q;
            for (; e + 4 < end; e += 8) {
                int s0 = col[e], s1 = col[e + 4];
                uint4 u0 = G[(long)s0 * 16 + seg];
                uint4 u1 = G[(long)s1 * 16 + seg];
                acc[0] += bf_lo(u0.x); acc[1] += bf_hi(u0.x);
                acc[2] += bf_lo(u0.y); acc[3] += bf_hi(u0.y);
                acc[4] += bf_lo(u0.z); acc[5] += bf_hi(u0.z);
                acc[6] += bf_lo(u0.w); acc[7] += bf_hi(u0.w);
                acc[0] += bf_lo(u1.x); acc[1] += bf_hi(u1.x);
                acc[2] += bf_lo(u1.y); acc[3] += bf_hi(u1.y);
                acc[4] += bf_lo(u1.z); acc[5] += bf_hi(u1.z);
                acc[6] += bf_lo(u1.w); acc[7] += bf_hi(u1.w);
            }
            if (e < end) {
                int s0 = col[e];
                uint4 u = G[(long)s0 * 16 + seg];
                acc[0] += bf_lo(u.x); acc[1] += bf_hi(u.x);
                acc[2] += bf_lo(u.y); acc[3] += bf_hi(u.y);
                acc[4] += bf_lo(u.z); acc[5] += bf_hi(u.z);
                acc[6] += bf_lo(u.w); acc[7] += bf_hi(u.w);
            }
        }
#pragma unroll
        for (int off = 16; off < 64; off <<= 1)
#pragma unroll
            for (int j = 0; j < 8; ++j) acc[j] += __shfl_xor(acc[j], off);

        if (q == 0) {
            uint4 pw = make_uint4(0u, 0u, 0u, 0u);
            if (r < N_NODES) {
                uint4 u = G[(long)r * 16 + seg];   // self-loop
                acc[0] += bf_lo(u.x); acc[1] += bf_hi(u.x);
                acc[2] += bf_lo(u.y); acc[3] += bf_hi(u.y);
                acc[4] += bf_lo(u.z); acc[5] += bf_hi(u.z);
                acc[6] += bf_lo(u.w); acc[7] += bf_hi(u.w);
                const float d = dis[r];
                float o[8];
                o[0] = fmaxf(acc[0] * d + bA.x, 0.f);
                o[1] = fmaxf(acc[1] * d + bA.y, 0.f);
                o[2] = fmaxf(acc[2] * d + bA.z, 0.f);
                o[3] = fmaxf(acc[3] * d + bA.w, 0.f);
                o[4] = fmaxf(acc[4] * d + bB.x, 0.f);
                o[5] = fmaxf(acc[5] * d + bB.y, 0.f);
                o[6] = fmaxf(acc[6] * d + bB.z, 0.f);
                o[7] = fmaxf(acc[7] * d + bB.w, 0.f);
                pw.x = pack2(o[0], o[1]); pw.y = pack2(o[2], o[3]);
                pw.z = pack2(o[4], o[5]); pw.w = pack2(o[6], o[7]);
            }
            *(uint4*)&a1s[(w * 16 + i) * XPAD + cl] = pw;
        }
    }
    __syncthreads();

    // MFMA: rows (w*16+m) x 64 cols
    const int m = lane & 15;
    const ushort_t* arow = &a1s[(w * 16 + m) * XPAD + q * 8];
    const ushort_t* brow = &ws[m * XPAD + q * 8];

    f32x4 acc2[4] = {};
#pragma unroll
    for (int k0 = 0; k0 < 128; k0 += 32) {
        bf16x8 a = *(const bf16x8*)(arow + k0);
#pragma unroll
        for (int nt = 0; nt < 4; ++nt) {
            bf16x8 b = *(const bf16x8*)(brow + nt * 16 * XPAD + k0);
            acc2[nt] = __builtin_amdgcn_mfma_f32_16x16x32_bf16(a, b, acc2[nt], 0, 0, 0);
        }
    }

#pragma unroll
    for (int reg = 0; reg < 4; ++reg) {
        int gr = row0 + w * 16 + q * 4 + reg;
        if (gr < N_NODES) {
            float d = dis[gr];
#pragma unroll
            for (int nt = 0; nt < 4; ++nt)
                g3[(long)gr * OUT_CH + nt * 16 + m] = f2bf(acc2[nt][reg] * d);
        }
    }
}

// ===== layer-2 aggregate (bf16 gather, fp32 acc) -> fp32 out =====

__global__ __launch_bounds__(256) void k_agg2(const int* __restrict__ row_ptr,
                                              const int* __restrict__ col,
                                              const float* __restrict__ dis,
                                              const ushort_t* __restrict__ g3,
                                              const float* __restrict__ b2,
                                              float* __restrict__ out) {
    int r = blockIdx.x * 4 + (threadIdx.x >> 6);
    if (r >= N_NODES) return;
    const int lane = threadIdx.x & 63;
    const int q = lane >> 3;
    const int seg = lane & 7;
    const int cl = seg << 3;
    const uint4* G = (const uint4*)g3;
    const int beg = row_ptr[r], end = row_ptr[r + 1];

    float acc[8] = {};
    int e = beg + q;
    for (; e + 8 < end; e += 16) {
        int s0 = col[e], s1 = col[e + 8];
        uint4 u0 = G[(long)s0 * 8 + seg];
        uint4 u1 = G[(long)s1 * 8 + seg];
        acc[0] += bf_lo(u0.x); acc[1] += bf_hi(u0.x);
        acc[2] += bf_lo(u0.y); acc[3] += bf_hi(u0.y);
        acc[4] += bf_lo(u0.z); acc[5] += bf_hi(u0.z);
        acc[6] += bf_lo(u0.w); acc[7] += bf_hi(u0.w);
        acc[0] += bf_lo(u1.x); acc[1] += bf_hi(u1.x);
        acc[2] += bf_lo(u1.y); acc[3] += bf_hi(u1.y);
        acc[4] += bf_lo(u1.z); acc[5] += bf_hi(u1.z);
        acc[6] += bf_lo(u1.w); acc[7] += bf_hi(u1.w);
    }
    if (e < end) {
        int s = col[e];
        uint4 u = G[(long)s * 8 + seg];
        acc[0] += bf_lo(u.x); acc[1] += bf_hi(u.x);
        acc[2] += bf_lo(u.y); acc[3] += bf_hi(u.y);
        acc[4] += bf_lo(u.z); acc[5] += bf_hi(u.z);
        acc[6] += bf_lo(u.w); acc[7] += bf_hi(u.w);
    }
#pragma unroll
    for (int off = 8; off < 64; off <<= 1)
#pragma unroll
        for (int j = 0; j < 8; ++j) acc[j] += __shfl_xor(acc[j], off);

    if (q == 0) {
        uint4 u = G[(long)r * 8 + seg];
        acc[0] += bf_lo(u.x); acc[1] += bf_hi(u.x);
        acc[2] += bf_lo(u.y); acc[3] += bf_hi(u.y);
        acc[4] += bf_lo(u.z); acc[5] += bf_hi(u.z);
        acc[6] += bf_lo(u.w); acc[7] += bf_hi(u.w);
        const float d = dis[r];
        float4 o0, o1;
        o0.x = acc[0] * d + b2[cl + 0];
        o0.y = acc[1] * d + b2[cl + 1];
        o0.z = acc[2] * d + b2[cl + 2];
        o0.w = acc[3] * d + b2[cl + 3];
        o1.x = acc[4] * d + b2[cl + 4];
        o1.y = acc[5] * d + b2[cl + 5];
        o1.z = acc[6] * d + b2[cl + 6];
        o1.w = acc[7] * d + b2[cl + 7];
        *(float4*)&out[(long)r * OUT_CH + cl] = o0;
        *(float4*)&out[(long)r * OUT_CH + cl + 4] = o1;
    }
}

// ================= launch =================

extern "C" void kernel_launch(void* const* d_in, const int* in_sizes, int n_in,
                              void* d_out, int out_size, void* d_ws, size_t ws_size,
                              hipStream_t stream) {
    const float* x   = (const float*)d_in[0];
    const int*   ei  = (const int*)d_in[1];
    const float* W1  = (const float*)d_in[2];
    const float* b1  = (const float*)d_in[3];
    const float* W2  = (const float*)d_in[4];
    const float* b2  = (const float*)d_in[5];
    float* out = (float*)d_out;

    const int* src = ei;
    const int* dst = ei + N_EDGES;

    char* p = (char*)d_ws;
    unsigned* rec = (unsigned*)p;         p += (long)N_EDGES * 4;
    int* col     = (int*)p;               p += (long)N_EDGES * 4;
    int* row_ptr = (int*)p;               p += 50064 * 4;
    int* bcnt    = (int*)p;               p += 256 * 4;
    int* bcur    = (int*)p;               p += 256 * 4;
    float* dis   = (float*)p;             p += 50048 * 4;
    ushort_t* W1t = (ushort_t*)p;         p += 128 * 128 * 2;
    ushort_t* W2t = (ushort_t*)p;         p += 128 * 64 * 2;
    ushort_t* g1  = (ushort_t*)p;         p += (long)N_NODES * HID * 2;
    ushort_t* g3  = (ushort_t*)p;

    const int B = 256;

    k_zero_prep<<<96, B, 0, stream>>>(W1, W2, W1t, W2t, bcnt, bcur);
    kb_hist<<<(N_EDGES + 8191) / 8192, B, 0, stream>>>(dst, bcnt);
    kb_scatter<<<(N_EDGES + 4095) / 4096, B, 0, stream>>>(src, dst, bcnt, bcur, rec);
    kc_csr<<<NBUCK, B, 0, stream>>>(bcnt, rec, row_ptr, dis, col);

    k_gemm1<<<(N_NODES + 63) / 64, B, 0, stream>>>(x, W1t, dis, g1);
    k_aggmm<<<(N_NODES + 63) / 64, B, 0, stream>>>(row_ptr, col, dis, g1, b1, W2t, g3);
    k_agg2<<<(N_NODES + 3) / 4, B, 0, stream>>>(row_ptr, col, dis, g3, b2, out);
}

// Round 9
// 179.104 us; speedup vs baseline: 1.2183x; 1.2183x over previous
//
#include <hip/hip_runtime.h>

#define N_NODES 50000
#define N_EDGES 800000
#define IN_CH   128
#define HID     128
#define OUT_CH  64

#define NBUCK 196          // ceil(50000/256) dst buckets
#define BCAP  5120         // slack capacity per bucket (mean 4082, +16 sigma)
#define XPAD  136          // 128 bf16 + 8 pad

#define SC_BLOCKS ((N_EDGES + 4095) / 4096)    // 196 scatter blocks
#define G1_BLOCKS ((N_NODES + 63) / 64)        // 782 gemm1 blocks

typedef __attribute__((ext_vector_type(8))) short bf16x8;
typedef __attribute__((ext_vector_type(4))) float f32x4;
typedef unsigned short ushort_t;

__device__ __forceinline__ unsigned short f2bf(float f) {
    unsigned u = __float_as_uint(f);
    u += 0x7fffu + ((u >> 16) & 1u);      // RNE
    return (unsigned short)(u >> 16);
}
__device__ __forceinline__ unsigned pack2(float a, float b) {
    return (unsigned)f2bf(a) | ((unsigned)f2bf(b) << 16);
}
__device__ __forceinline__ float bf_lo(unsigned u) { return __uint_as_float(u << 16); }
__device__ __forceinline__ float bf_hi(unsigned u) { return __uint_as_float(u & 0xffff0000u); }

// ========= setup: zero bucket cursors + bf16-transpose weights =========

__global__ __launch_bounds__(256) void k_prep(const float* __restrict__ W1,
                                              const float* __restrict__ W2,
                                              ushort_t* __restrict__ W1t,
                                              ushort_t* __restrict__ W2t,
                                              int* __restrict__ bcur) {
    if (blockIdx.x == 0 && threadIdx.x < NBUCK) bcur[threadIdx.x] = 0;
    int i = blockIdx.x * 256 + threadIdx.x;
    if (i < 128 * 128) {
        int k = i >> 7, c = i & 127;
        W1t[c * 128 + k] = f2bf(W1[k * 128 + c]);
    } else {
        int j = i - 128 * 128;
        if (j < 128 * 64) {
            int k = j >> 6, c = j & 63;
            W2t[c * 128 + k] = f2bf(W2[k * 64 + c]);
        }
    }
}

// ========= fat kernel: bucket-scatter (blocks 0..195) ∪ MFMA GEMM1 (rest) =========
// Independent workloads, both depend only on k_prep; one launch overlaps them.

__global__ __launch_bounds__(256) void k_fat(const int* __restrict__ src,
                                             const int* __restrict__ dst,
                                             int* __restrict__ bcur,
                                             unsigned* __restrict__ rec,
                                             const float* __restrict__ x,
                                             const ushort_t* __restrict__ W1t,
                                             ushort_t* __restrict__ g) {
    __shared__ char smem[52224];   // gemm1: 17408 xs + 34816 ws; scatter: 2KB hists
    const int tid = threadIdx.x;

    if (blockIdx.x < SC_BLOCKS) {
        // ---- scatter: pack (local_dst<<16 | src) into slack bucket runs ----
        int* lh    = (int*)smem;             // NBUCK counts
        int* gbase = (int*)(smem + 1024);    // NBUCK reserved bases
        for (int i = tid; i < NBUCK; i += 256) lh[i] = 0;
        __syncthreads();
        int base = blockIdx.x * 4096;
#pragma unroll 4
        for (int k = 0; k < 16; ++k) {
            int e = base + k * 256 + tid;
            if (e < N_EDGES) atomicAdd(&lh[dst[e] >> 8], 1);
        }
        __syncthreads();
        for (int i = tid; i < NBUCK; i += 256) {
            int c = lh[i];
            gbase[i] = c ? (i * BCAP + atomicAdd(&bcur[i], c)) : 0;
        }
        __syncthreads();
        for (int i = tid; i < NBUCK; i += 256) lh[i] = 0;
        __syncthreads();
#pragma unroll 4
        for (int k = 0; k < 16; ++k) {
            int e = base + k * 256 + tid;
            if (e < N_EDGES) {
                int d = dst[e], b = d >> 8;
                int rk = atomicAdd(&lh[b], 1);
                int pos = gbase[b] + rk;
                if (pos < (b + 1) * BCAP)   // overflow guard (never hits for this input)
                    rec[pos] = (unsigned)src[e] | ((unsigned)(d & 255) << 16);
            }
        }
    } else {
        // ---- MFMA GEMM1: g1 = bf16((x @ W1) * dis-less; dis applied at epilogue? no:
        // dis not ready yet (CSR not built) -> fold dis into agg1 instead? No:
        // g1 must be pre-scaled by dis[src]. dis comes from kc_csr which runs AFTER.
        // Solution: g1 stores un-scaled (x@W1); agg1 scales each gathered row by
        // dis[src]? That changes gather cost. Instead: keep scaling by dis in agg
        // via norm folding: sum over src of dis[src]*row[src] == gather of
        // (dis-prescaled rows). We prescale HERE using degree-free trick is
        // impossible -> so g1 is written UNSCALED and agg1 multiplies by dis[s].
        ushort_t* xs = (ushort_t*)smem;
        ushort_t* ws = (ushort_t*)(smem + 17408);
        const int bid = blockIdx.x - SC_BLOCKS;
        const int row0 = bid * 64;

        for (int i = tid; i < 64 * 32; i += 256) {
            int r = i >> 5, k4 = (i & 31) << 2;
            int gr = row0 + r;
            float4 v = make_float4(0.f, 0.f, 0.f, 0.f);
            if (gr < N_NODES) v = *(const float4*)&x[(long)gr * IN_CH + k4];
            ushort4 u;
            u.x = f2bf(v.x); u.y = f2bf(v.y); u.z = f2bf(v.z); u.w = f2bf(v.w);
            *(ushort4*)&xs[r * XPAD + k4] = u;
        }
        for (int i = tid; i < 128 * 16; i += 256) {
            int c = i >> 4, seg = i & 15;
            *(uint4*)&ws[c * XPAD + seg * 8] = *(const uint4*)&W1t[c * 128 + seg * 8];
        }
        __syncthreads();

        const int w = tid >> 6, lane = tid & 63;
        const int m = lane & 15, q = lane >> 4;
        const ushort_t* arow = &xs[(w * 16 + m) * XPAD + q * 8];
        const ushort_t* brow = &ws[m * XPAD + q * 8];

        f32x4 acc[8] = {};
#pragma unroll
        for (int k0 = 0; k0 < 128; k0 += 32) {
            bf16x8 a = *(const bf16x8*)(arow + k0);
#pragma unroll
            for (int nt = 0; nt < 8; ++nt) {
                bf16x8 b = *(const bf16x8*)(brow + nt * 16 * XPAD + k0);
                acc[nt] = __builtin_amdgcn_mfma_f32_16x16x32_bf16(a, b, acc[nt], 0, 0, 0);
            }
        }

#pragma unroll
        for (int reg = 0; reg < 4; ++reg) {
            int gr = row0 + w * 16 + q * 4 + reg;
            if (gr < N_NODES) {
#pragma unroll
                for (int nt = 0; nt < 8; ++nt)
                    g[(long)gr * HID + nt * 16 + m] = f2bf(acc[nt][reg]);
            }
        }
    }
}

// ========= per-bucket CSR: hist256 -> row_beg/row_end/dis, fill col slice =========

__global__ __launch_bounds__(256) void kc_csr(const int* __restrict__ bcur,
                                              const unsigned* __restrict__ rec,
                                              int* __restrict__ row_beg,
                                              int* __restrict__ row_end,
                                              float* __restrict__ dis,
                                              int* __restrict__ col) {
    __shared__ int lh[256];
    __shared__ int cur[256];
    __shared__ int s[256];
    const int b = blockIdx.x, t = threadIdx.x;
    const int lo = b * BCAP;
    const int cnt = min(bcur[b], BCAP);
    const int hi = lo + cnt;

    lh[t] = 0;
    __syncthreads();
    for (int j = lo + t; j < hi; j += 256)
        atomicAdd(&lh[rec[j] >> 16], 1);
    __syncthreads();
    int deg = lh[t];
    s[t] = deg;
    __syncthreads();
    for (int off = 1; off < 256; off <<= 1) {
        int u = (t >= off) ? s[t - off] : 0;
        __syncthreads();
        s[t] += u;
        __syncthreads();
    }
    int gp = lo + s[t] - deg;
    int node = (b << 8) + t;
    if (node < N_NODES) {
        row_beg[node] = gp;
        row_end[node] = gp + deg;
        dis[node] = rsqrtf((float)deg + 1.0f);
    }
    cur[t] = gp;
    __syncthreads();
    for (int j = lo + t; j < hi; j += 256) {
        unsigned r = rec[j];
        int pos = atomicAdd(&cur[r >> 16], 1);
        col[pos] = (int)(r & 0xffffu);
    }
}

// ===== layer-1 aggregate: a1 = bf16(relu(dis[r]*(sum dis[s]*g1[s] + dis[r]*g1[r]) + b1))
// g1 is UNSCALED (x@W1); dis[s] applied per gathered row (one extra fmul per row).

__global__ __launch_bounds__(256) void k_agg1(const int* __restrict__ row_beg,
                                              const int* __restrict__ row_end,
                                              const int* __restrict__ col,
                                              const float* __restrict__ dis,
                                              const ushort_t* __restrict__ g1,
                                              const float* __restrict__ b1,
                                              ushort_t* __restrict__ a1) {
    int r = blockIdx.x * 4 + (threadIdx.x >> 6);
    if (r >= N_NODES) return;
    const int lane = threadIdx.x & 63;
    const int q = lane >> 4;            // edge slot 0..3
    const int seg = lane & 15;          // 16B segment
    const int cl = seg << 3;
    const uint4* G = (const uint4*)g1;
    const int beg = row_beg[r], end = row_end[r];

    float acc[8] = {};
    int e = beg + q;
    for (; e + 4 < end; e += 8) {
        int s0 = col[e], s1 = col[e + 4];
        float d0 = dis[s0], d1 = dis[s1];
        uint4 u0 = G[(long)s0 * 16 + seg];
        uint4 u1 = G[(long)s1 * 16 + seg];
        acc[0] += bf_lo(u0.x) * d0; acc[1] += bf_hi(u0.x) * d0;
        acc[2] += bf_lo(u0.y) * d0; acc[3] += bf_hi(u0.y) * d0;
        acc[4] += bf_lo(u0.z) * d0; acc[5] += bf_hi(u0.z) * d0;
        acc[6] += bf_lo(u0.w) * d0; acc[7] += bf_hi(u0.w) * d0;
        acc[0] += bf_lo(u1.x) * d1; acc[1] += bf_hi(u1.x) * d1;
        acc[2] += bf_lo(u1.y) * d1; acc[3] += bf_hi(u1.y) * d1;
        acc[4] += bf_lo(u1.z) * d1; acc[5] += bf_hi(u1.z) * d1;
        acc[6] += bf_lo(u1.w) * d1; acc[7] += bf_hi(u1.w) * d1;
    }
    if (e < end) {
        int s0 = col[e];
        float d0 = dis[s0];
        uint4 u = G[(long)s0 * 16 + seg];
        acc[0] += bf_lo(u.x) * d0; acc[1] += bf_hi(u.x) * d0;
        acc[2] += bf_lo(u.y) * d0; acc[3] += bf_hi(u.y) * d0;
        acc[4] += bf_lo(u.z) * d0; acc[5] += bf_hi(u.z) * d0;
        acc[6] += bf_lo(u.w) * d0; acc[7] += bf_hi(u.w) * d0;
    }
#pragma unroll
    for (int off = 16; off < 64; off <<= 1)
#pragma unroll
        for (int j = 0; j < 8; ++j) acc[j] += __shfl_xor(acc[j], off);

    if (q == 0) {
        const float d = dis[r];
        uint4 u = G[(long)r * 16 + seg];    // self-loop (scaled by dis[r])
        acc[0] += bf_lo(u.x) * d; acc[1] += bf_hi(u.x) * d;
        acc[2] += bf_lo(u.y) * d; acc[3] += bf_hi(u.y) * d;
        acc[4] += bf_lo(u.z) * d; acc[5] += bf_hi(u.z) * d;
        acc[6] += bf_lo(u.w) * d; acc[7] += bf_hi(u.w) * d;
        float o[8];
#pragma unroll
        for (int j = 0; j < 8; ++j) o[j] = fmaxf(acc[j] * d + b1[cl + j], 0.f);
        uint4 pw;
        pw.x = pack2(o[0], o[1]); pw.y = pack2(o[2], o[3]);
        pw.z = pack2(o[4], o[5]); pw.w = pack2(o[6], o[7]);
        *(uint4*)&a1[(long)r * HID + cl] = pw;
    }
}

// ====== MFMA GEMM2: g3 = bf16((a1 @ W2) * dis[row]); 64 rows x 64 cols/block ======

__global__ __launch_bounds__(256) void k_gemm2(const ushort_t* __restrict__ a1,
                                               const ushort_t* __restrict__ W2t,
                                               const float* __restrict__ dis,
                                               ushort_t* __restrict__ g) {
    __shared__ ushort_t xs[64 * XPAD];
    __shared__ ushort_t ws[64 * XPAD];
    const int tid = threadIdx.x;
    const int row0 = blockIdx.x * 64;

    for (int i = tid; i < 64 * 16; i += 256) {
        int r = i >> 4, seg = i & 15;
        int gr = row0 + r;
        uint4 v = make_uint4(0u, 0u, 0u, 0u);
        if (gr < N_NODES) v = *(const uint4*)&a1[(long)gr * HID + seg * 8];
        *(uint4*)&xs[r * XPAD + seg * 8] = v;
    }
    for (int i = tid; i < 64 * 16; i += 256) {
        int c = i >> 4, seg = i & 15;
        *(uint4*)&ws[c * XPAD + seg * 8] = *(const uint4*)&W2t[c * 128 + seg * 8];
    }
    __syncthreads();

    const int w = tid >> 6, lane = tid & 63;
    const int m = lane & 15, q = lane >> 4;
    const ushort_t* arow = &xs[(w * 16 + m) * XPAD + q * 8];
    const ushort_t* brow = &ws[m * XPAD + q * 8];

    f32x4 acc[4] = {};
#pragma unroll
    for (int k0 = 0; k0 < 128; k0 += 32) {
        bf16x8 a = *(const bf16x8*)(arow + k0);
#pragma unroll
        for (int nt = 0; nt < 4; ++nt) {
            bf16x8 b = *(const bf16x8*)(brow + nt * 16 * XPAD + k0);
            acc[nt] = __builtin_amdgcn_mfma_f32_16x16x32_bf16(a, b, acc[nt], 0, 0, 0);
        }
    }

#pragma unroll
    for (int reg = 0; reg < 4; ++reg) {
        int gr = row0 + w * 16 + q * 4 + reg;
        if (gr < N_NODES) {
            float d = dis[gr];
#pragma unroll
            for (int nt = 0; nt < 4; ++nt)
                g[(long)gr * OUT_CH + nt * 16 + m] = f2bf(acc[nt][reg] * d);
        }
    }
}

// ===== layer-2 aggregate (bf16 gather, fp32 acc) -> fp32 out =====
// g3 is pre-scaled by dis[src] (gemm2 epilogue), so plain sum here.

__global__ __launch_bounds__(256) void k_agg2(const int* __restrict__ row_beg,
                                              const int* __restrict__ row_end,
                                              const int* __restrict__ col,
                                              const float* __restrict__ dis,
                                              const ushort_t* __restrict__ g3,
                                              const float* __restrict__ b2,
                                              float* __restrict__ out) {
    int r = blockIdx.x * 4 + (threadIdx.x >> 6);
    if (r >= N_NODES) return;
    const int lane = threadIdx.x & 63;
    const int q = lane >> 3;
    const int seg = lane & 7;
    const int cl = seg << 3;
    const uint4* G = (const uint4*)g3;
    const int beg = row_beg[r], end = row_end[r];

    float acc[8] = {};
    int e = beg + q;
    for (; e + 8 < end; e += 16) {
        int s0 = col[e], s1 = col[e + 8];
        uint4 u0 = G[(long)s0 * 8 + seg];
        uint4 u1 = G[(long)s1 * 8 + seg];
        acc[0] += bf_lo(u0.x); acc[1] += bf_hi(u0.x);
        acc[2] += bf_lo(u0.y); acc[3] += bf_hi(u0.y);
        acc[4] += bf_lo(u0.z); acc[5] += bf_hi(u0.z);
        acc[6] += bf_lo(u0.w); acc[7] += bf_hi(u0.w);
        acc[0] += bf_lo(u1.x); acc[1] += bf_hi(u1.x);
        acc[2] += bf_lo(u1.y); acc[3] += bf_hi(u1.y);
        acc[4] += bf_lo(u1.z); acc[5] += bf_hi(u1.z);
        acc[6] += bf_lo(u1.w); acc[7] += bf_hi(u1.w);
    }
    if (e < end) {
        int s = col[e];
        uint4 u = G[(long)s * 8 + seg];
        acc[0] += bf_lo(u.x); acc[1] += bf_hi(u.x);
        acc[2] += bf_lo(u.y); acc[3] += bf_hi(u.y);
        acc[4] += bf_lo(u.z); acc[5] += bf_hi(u.z);
        acc[6] += bf_lo(u.w); acc[7] += bf_hi(u.w);
    }
#pragma unroll
    for (int off = 8; off < 64; off <<= 1)
#pragma unroll
        for (int j = 0; j < 8; ++j) acc[j] += __shfl_xor(acc[j], off);

    if (q == 0) {
        uint4 u = G[(long)r * 8 + seg];
        acc[0] += bf_lo(u.x); acc[1] += bf_hi(u.x);
        acc[2] += bf_lo(u.y); acc[3] += bf_hi(u.y);
        acc[4] += bf_lo(u.z); acc[5] += bf_hi(u.z);
        acc[6] += bf_lo(u.w); acc[7] += bf_hi(u.w);
        const float d = dis[r];
        float4 o0, o1;
        o0.x = acc[0] * d + b2[cl + 0];
        o0.y = acc[1] * d + b2[cl + 1];
        o0.z = acc[2] * d + b2[cl + 2];
        o0.w = acc[3] * d + b2[cl + 3];
        o1.x = acc[4] * d + b2[cl + 4];
        o1.y = acc[5] * d + b2[cl + 5];
        o1.z = acc[6] * d + b2[cl + 6];
        o1.w = acc[7] * d + b2[cl + 7];
        *(float4*)&out[(long)r * OUT_CH + cl] = o0;
        *(float4*)&out[(long)r * OUT_CH + cl + 4] = o1;
    }
}

// ================= launch =================

extern "C" void kernel_launch(void* const* d_in, const int* in_sizes, int n_in,
                              void* d_out, int out_size, void* d_ws, size_t ws_size,
                              hipStream_t stream) {
    const float* x   = (const float*)d_in[0];
    const int*   ei  = (const int*)d_in[1];
    const float* W1  = (const float*)d_in[2];
    const float* b1  = (const float*)d_in[3];
    const float* W2  = (const float*)d_in[4];
    const float* b2  = (const float*)d_in[5];
    float* out = (float*)d_out;

    const int* src = ei;
    const int* dst = ei + N_EDGES;

    char* p = (char*)d_ws;
    unsigned* rec = (unsigned*)p;         p += (long)NBUCK * BCAP * 4;   // 4.0 MB slack
    int* col     = (int*)p;               p += (long)NBUCK * BCAP * 4;   // 4.0 MB slack
    int* row_beg = (int*)p;               p += 50048 * 4;
    int* row_end = (int*)p;               p += 50048 * 4;
    int* bcur    = (int*)p;               p += 256 * 4;
    float* dis   = (float*)p;             p += 50048 * 4;
    ushort_t* W1t = (ushort_t*)p;         p += 128 * 128 * 2;
    ushort_t* W2t = (ushort_t*)p;         p += 128 * 64 * 2;
    ushort_t* g1  = (ushort_t*)p;         p += (long)N_NODES * HID * 2;
    ushort_t* a1  = (ushort_t*)p;         p += (long)N_NODES * HID * 2;
    ushort_t* g3  = (ushort_t*)p;

    const int B = 256;

    k_prep<<<96, B, 0, stream>>>(W1, W2, W1t, W2t, bcur);
    k_fat<<<SC_BLOCKS + G1_BLOCKS, B, 0, stream>>>(src, dst, bcur, rec, x, W1t, g1);
    kc_csr<<<NBUCK, B, 0, stream>>>(bcur, rec, row_beg, row_end, dis, col);
    k_agg1<<<(N_NODES + 3) / 4, B, 0, stream>>>(row_beg, row_end, col, dis, g1, b1, a1);
    k_gemm2<<<(N_NODES + 63) / 64, B, 0, stream>>>(a1, W2t, dis, g3);
    k_agg2<<<(N_NODES + 3) / 4, B, 0, stream>>>(row_beg, row_end, col, dis, g3, b2, out);
}